// Round 1
// 371.624 us; speedup vs baseline: 1.0109x; 1.0109x over previous
//
#include <hip/hip_runtime.h>
#include <math.h>

typedef __attribute__((ext_vector_type(8))) short bf16x8;
typedef __attribute__((ext_vector_type(4))) float f32x4;

static __device__ __forceinline__ short f2bf(float f) {
    union { float f; unsigned u; } v; v.f = f;
    unsigned r = v.u + 0x7FFFu + ((v.u >> 16) & 1u);
    return (short)(r >> 16);
}

static __device__ __forceinline__ float bf2f(short s) {
    union { unsigned u; float f; } v;
    v.u = ((unsigned)(unsigned short)s) << 16;
    return v.f;
}

// ---------------------------------------------------------------------------
// Physical k-layout of F / W columns (4096), co packed innermost:
//   big n in {0,1}:   phys = n*1024 + pos*4 + co    (pos 0..255)
//   small n in {2..9}: phys = 2048 + (n-2)*256 + pos*4 + co (pos 0..63)
// ---------------------------------------------------------------------------

// K0 (merged): blocks [0,4096) build W_eff; blocks [4096,20480) run the
// conv+BN+ReLU+pool branches. W-blocks dispatch first and overlap with the
// branch blocks, saving one kernel launch + drain bubble.
__global__ __launch_bounds__(256) void k_prep(
    const float* __restrict__ x,      // (4096,3,64,64)
    const float* __restrict__ conv_w, // (10,4,3,3,3)
    const float* __restrict__ conv_b,
    const float* __restrict__ bn_g,
    const float* __restrict__ bn_b,
    const float* __restrict__ bn_m,
    const float* __restrict__ bn_v,
    const float* __restrict__ cut_w_big,   // (2,256,1024)
    const float* __restrict__ cut_w_small, // (8,256,256)
    const float* __restrict__ b_mat,       // (10,256)
    const float* __restrict__ h_mat,       // (10,64,5)
    const float* __restrict__ a_mat,       // (256,5,5)
    const float* __restrict__ indicator,   // (256,64)
    short* __restrict__ F,            // (4096,4096) bf16
    short* __restrict__ W)            // (256,4096) bf16
{
    if (blockIdx.x < 4096) {
        // ---- W_eff build: W[j,k] = cut_w * coeff[n(k), j] ----
        int bx = blockIdx.x;
        int tid0 = bx << 8;
        int j = tid0 >> 12;               // block-uniform
        int kbase = tid0 & 4095;          // block-uniform
        int n = (kbase < 2048) ? (kbase >> 10) : 2 + ((kbase - 2048) >> 8);

        float arow[5];
#pragma unroll
        for (int c = 0; c < 5; ++c) {
            float s = 0.f;
#pragma unroll
            for (int m = 0; m < 5; ++m) s += a_mat[j * 25 + c * 5 + m];
            arow[c] = s;
        }
        int lane = threadIdx.x & 63;
        float hs = 0.f;
#pragma unroll
        for (int c = 0; c < 5; ++c) hs += h_mat[(n * 64 + lane) * 5 + c] * arow[c];
        float v = indicator[j * 64 + lane] * hs;
#pragma unroll
        for (int off = 32; off >= 1; off >>= 1) v += __shfl_xor(v, off);
        float coeff = b_mat[n * 256 + j] * v;

        int tid = tid0 + threadIdx.x;
        int k = tid & 4095;
        float w;
        if (k < 2048) {
            int nn = k >> 10;
            int r = k & 1023;
            int pos = r >> 2, co = r & 3;
            w = cut_w_big[((nn * 256 + j) << 10) + co * 256 + pos];
        } else {
            int kk2 = k - 2048;
            int nn = kk2 >> 8;
            int r = kk2 & 255;
            int pos = r >> 2, co = r & 3;
            w = cut_w_small[((nn * 256 + j) << 8) + co * 64 + pos];
        }
        W[tid] = f2bf(w * coeff);
        return;
    }

    // ---- conv branches ----
    // big:   per ci: E[34][24] + O[34][24] = 1632 floats, x3 = 4896
    // small: per page (ci*4+img): E[18][12]+O[18][12] = 432, x12 = 5184
    __shared__ __align__(16) float in_s[5184];
    __shared__ float bn_a[4], bn_c[4];
    int t = threadIdx.x;
    int bx = blockIdx.x - 4096;

    if (bx < 8192) {
        // ---- big branch: 32x32 slice, 1 image/block ----
        int n = bx >> 12;
        int b = bx & 4095;
        int r0 = 32 * n;
        // full-tile zero (4896 floats = 1224 float4)
        {
            float4 z4 = make_float4(0.f, 0.f, 0.f, 0.f);
            float4* zp = (float4*)in_s;
            for (int i = t; i < 1224; i += 256) zp[i] = z4;
        }
        if (t < 4) {
            float scale = bn_g[n * 4 + t] * rsqrtf(bn_v[n * 4 + t] + 1e-5f);
            bn_a[t] = scale;
            bn_c[t] = (conv_b[n * 4 + t] - bn_m[n * 4 + t]) * scale + bn_b[n * 4 + t];
        }
        __syncthreads();
        // stage interior rows 1..32: 768 float4 (3/thread)
        for (int i = t; i < 768; i += 256) {
            int ci = i >> 8, rem = i & 255, yy = rem >> 3, xq = rem & 7;
            float4 v = *(const float4*)(x + ((size_t)(b * 3 + ci) * 64 + r0 + yy) * 64 + xq * 4);
            int eb = ci * 1632 + (yy + 1) * 24;
            int ob = eb + 816;
            *(float2*)&in_s[eb + 2 * xq] = make_float2(v.x, v.z);   // E[2xq],E[2xq+1]
            in_s[ob + 2 * xq + 1] = v.y;                            // O: col 4xq+1
            in_s[ob + 2 * xq + 2] = v.w;                            // O: col 4xq+3
        }
        __syncthreads();

        int py = t >> 4, px = t & 15;
        float s[4][4];
#pragma unroll
        for (int a = 0; a < 4; ++a)
#pragma unroll
            for (int p = 0; p < 4; ++p) s[a][p] = 0.f;
        const float* wp = conv_w + n * 108;
#pragma unroll
        for (int ci = 0; ci < 3; ++ci) {
            float wv[16];
#pragma unroll
            for (int dy = 0; dy < 4; ++dy) {
                int rowb = ci * 1632 + (2 * py + dy) * 24 + px;
                float e0 = in_s[rowb];            // col 2px
                float e1 = in_s[rowb + 1];        // col 2px+2
                float o0 = in_s[rowb + 816];      // col 2px-1
                float o1 = in_s[rowb + 817];      // col 2px+1
                wv[dy * 4 + 0] = o0; wv[dy * 4 + 1] = e0;
                wv[dy * 4 + 2] = o1; wv[dy * 4 + 3] = e1;
            }
#pragma unroll
            for (int co = 0; co < 4; ++co) {
                const float* kk = wp + co * 27 + ci * 9;
                float k0 = kk[0], k1 = kk[1], k2 = kk[2], k3 = kk[3], k4 = kk[4],
                      k5 = kk[5], k6 = kk[6], k7 = kk[7], k8 = kk[8];
                s[co][0] += wv[0] * k0 + wv[1] * k1 + wv[2] * k2 + wv[4] * k3 + wv[5] * k4 + wv[6] * k5 + wv[8] * k6 + wv[9] * k7 + wv[10] * k8;
                s[co][1] += wv[1] * k0 + wv[2] * k1 + wv[3] * k2 + wv[5] * k3 + wv[6] * k4 + wv[7] * k5 + wv[9] * k6 + wv[10] * k7 + wv[11] * k8;
                s[co][2] += wv[4] * k0 + wv[5] * k1 + wv[6] * k2 + wv[8] * k3 + wv[9] * k4 + wv[10] * k5 + wv[12] * k6 + wv[13] * k7 + wv[14] * k8;
                s[co][3] += wv[5] * k0 + wv[6] * k1 + wv[7] * k2 + wv[9] * k3 + wv[10] * k4 + wv[11] * k5 + wv[13] * k6 + wv[14] * k7 + wv[15] * k8;
            }
        }
        short4 pk;
        {
            float m[4];
#pragma unroll
            for (int co = 0; co < 4; ++co) {
                float a = bn_a[co], c2 = bn_c[co];
                float v0 = fmaxf(s[co][0] * a + c2, 0.f);
                float v1 = fmaxf(s[co][1] * a + c2, 0.f);
                float v2 = fmaxf(s[co][2] * a + c2, 0.f);
                float v3 = fmaxf(s[co][3] * a + c2, 0.f);
                m[co] = fmaxf(fmaxf(v0, v1), fmaxf(v2, v3));
            }
            pk.x = f2bf(m[0]); pk.y = f2bf(m[1]); pk.z = f2bf(m[2]); pk.w = f2bf(m[3]);
        }
        *(short4*)&F[(size_t)b * 4096 + n * 1024 + t * 4] = pk;
    } else {
        // ---- small branches: 16x16 slices, 4 images/block ----
        int i2 = bx - 8192;
        int n = 2 + (i2 >> 10);
        int g = i2 & 1023;
        int b0 = g * 4;
        int r0 = 16 * ((n - 2) & 3);
        int c0 = 32 + 16 * ((n - 2) >> 2);
        // full-tile zero (5184 floats = 1296 float4)
        {
            float4 z4 = make_float4(0.f, 0.f, 0.f, 0.f);
            float4* zp = (float4*)in_s;
            for (int i = t; i < 1296; i += 256) zp[i] = z4;
        }
        if (t < 4) {
            float scale = bn_g[n * 4 + t] * rsqrtf(bn_v[n * 4 + t] + 1e-5f);
            bn_a[t] = scale;
            bn_c[t] = (conv_b[n * 4 + t] - bn_m[n * 4 + t]) * scale + bn_b[n * 4 + t];
        }
        __syncthreads();
        // stage interior: 768 float4 (3/thread), page = ci*4+img
        for (int i = t; i < 768; i += 256) {
            int page = i >> 6, rem = i & 63, yy = rem >> 2, xq = rem & 3;
            int ci = page >> 2, img = page & 3;
            float4 v = *(const float4*)(x + ((size_t)((b0 + img) * 3 + ci) * 64 + r0 + yy) * 64 + c0 + xq * 4);
            int eb = page * 432 + (yy + 1) * 12;
            int ob = eb + 216;
            *(float2*)&in_s[eb + 2 * xq] = make_float2(v.x, v.z);
            in_s[ob + 2 * xq + 1] = v.y;
            in_s[ob + 2 * xq + 2] = v.w;
        }
        __syncthreads();

        int img = t >> 6;
        int pos = t & 63;
        int py = pos >> 3, px = pos & 7;
        float s[4][4];
#pragma unroll
        for (int a = 0; a < 4; ++a)
#pragma unroll
            for (int p = 0; p < 4; ++p) s[a][p] = 0.f;
        const float* wp = conv_w + n * 108;
#pragma unroll
        for (int ci = 0; ci < 3; ++ci) {
            float wv[16];
            int pageb = (ci * 4 + img) * 432;
#pragma unroll
            for (int dy = 0; dy < 4; ++dy) {
                int rowb = pageb + (2 * py + dy) * 12 + px;
                float e0 = in_s[rowb];
                float e1 = in_s[rowb + 1];
                float o0 = in_s[rowb + 216];
                float o1 = in_s[rowb + 217];
                wv[dy * 4 + 0] = o0; wv[dy * 4 + 1] = e0;
                wv[dy * 4 + 2] = o1; wv[dy * 4 + 3] = e1;
            }
#pragma unroll
            for (int co = 0; co < 4; ++co) {
                const float* kk = wp + co * 27 + ci * 9;
                float k0 = kk[0], k1 = kk[1], k2 = kk[2], k3 = kk[3], k4 = kk[4],
                      k5 = kk[5], k6 = kk[6], k7 = kk[7], k8 = kk[8];
                s[co][0] += wv[0] * k0 + wv[1] * k1 + wv[2] * k2 + wv[4] * k3 + wv[5] * k4 + wv[6] * k5 + wv[8] * k6 + wv[9] * k7 + wv[10] * k8;
                s[co][1] += wv[1] * k0 + wv[2] * k1 + wv[3] * k2 + wv[5] * k3 + wv[6] * k4 + wv[7] * k5 + wv[9] * k6 + wv[10] * k7 + wv[11] * k8;
                s[co][2] += wv[4] * k0 + wv[5] * k1 + wv[6] * k2 + wv[8] * k3 + wv[9] * k4 + wv[10] * k5 + wv[12] * k6 + wv[13] * k7 + wv[14] * k8;
                s[co][3] += wv[5] * k0 + wv[6] * k1 + wv[7] * k2 + wv[9] * k3 + wv[10] * k4 + wv[11] * k5 + wv[13] * k6 + wv[14] * k7 + wv[15] * k8;
            }
        }
        short4 pk;
        {
            float m[4];
#pragma unroll
            for (int co = 0; co < 4; ++co) {
                float a = bn_a[co], c2 = bn_c[co];
                float v0 = fmaxf(s[co][0] * a + c2, 0.f);
                float v1 = fmaxf(s[co][1] * a + c2, 0.f);
                float v2 = fmaxf(s[co][2] * a + c2, 0.f);
                float v3 = fmaxf(s[co][3] * a + c2, 0.f);
                m[co] = fmaxf(fmaxf(v0, v1), fmaxf(v2, v3));
            }
            pk.x = f2bf(m[0]); pk.y = f2bf(m[1]); pk.z = f2bf(m[2]); pk.w = f2bf(m[3]);
        }
        *(short4*)&F[(size_t)(b0 + img) * 4096 + 2048 + (n - 2) * 256 + pos * 4] = pk;
    }
}

// ---------------------------------------------------------------------------
// K2: bf16 MFMA GEMM, split-K=8. P now stored as bf16 (halves P HBM traffic;
// partials are O(3e-3) and downstream logits are O(1e-4), so bf16 rounding
// of partials is far below the existing bf16-F/W noise floor).
// ---------------------------------------------------------------------------
__global__ __launch_bounds__(256) void k_gemm(
    const short* __restrict__ F, // (4096,4096) bf16
    const short* __restrict__ W, // (256,4096) bf16
    short* __restrict__ P)       // (8,4096,256) bf16
{
    __shared__ short As[128 * 64];
    __shared__ short Bs[128 * 64];
    int bx = blockIdx.x;          // 512 = 32 mtiles x 2 jtiles x 8 ksplit
    int mt = bx & 31;
    int jt = (bx >> 5) & 1;
    int ks = bx >> 6;
    int t = threadIdx.x;
    int m0 = mt << 7, j0 = jt << 7;

    int lane = t & 63;
    int wave = t >> 6;
    int wm = wave & 1, wn = wave >> 1;
    int l16 = lane & 15, quad = lane >> 4;

    f32x4 acc[4][4];
#pragma unroll
    for (int i = 0; i < 4; ++i)
#pragma unroll
        for (int j = 0; j < 4; ++j) acc[i][j] = (f32x4){0.f, 0.f, 0.f, 0.f};

    for (int it = 0; it < 8; ++it) {
        int k0 = (ks << 9) + (it << 6);
#pragma unroll
        for (int r = 0; r < 4; ++r) {
            int c = (r << 8) + t;
            int row = c >> 3, sgl = c & 7;
            int gsw = sgl ^ (row & 7);
            const short* gpA = F + ((size_t)(m0 + row) << 12) + k0 + (gsw << 3);
            const short* gpB = W + ((size_t)(j0 + row) << 12) + k0 + (gsw << 3);
            __builtin_amdgcn_global_load_lds(
                (const __attribute__((address_space(1))) void*)gpA,
                (__attribute__((address_space(3))) void*)(As + (c << 3)), 16, 0, 0);
            __builtin_amdgcn_global_load_lds(
                (const __attribute__((address_space(1))) void*)gpB,
                (__attribute__((address_space(3))) void*)(Bs + (c << 3)), 16, 0, 0);
        }
        __syncthreads();
#pragma unroll
        for (int ks2 = 0; ks2 < 2; ++ks2) {
            bf16x8 af[4], bfr[4];
#pragma unroll
            for (int mi = 0; mi < 4; ++mi) {
                int row = (wm << 6) + (mi << 4) + l16;
                int q = (ks2 << 2) + quad;
                int sl = q ^ (row & 7);
                af[mi] = *(const bf16x8*)&As[(row << 6) + (sl << 3)];
            }
#pragma unroll
            for (int ni = 0; ni < 4; ++ni) {
                int row = (wn << 6) + (ni << 4) + l16;
                int q = (ks2 << 2) + quad;
                int sl = q ^ (row & 7);
                bfr[ni] = *(const bf16x8*)&Bs[(row << 6) + (sl << 3)];
            }
#pragma unroll
            for (int mi = 0; mi < 4; ++mi)
#pragma unroll
                for (int ni = 0; ni < 4; ++ni)
                    acc[mi][ni] = __builtin_amdgcn_mfma_f32_16x16x32_bf16(
                        af[mi], bfr[ni], acc[mi][ni], 0, 0, 0);
        }
        __syncthreads();
    }

    short* Pp = P + ((size_t)ks << 20);
#pragma unroll
    for (int mi = 0; mi < 4; ++mi)
#pragma unroll
        for (int ni = 0; ni < 4; ++ni) {
            int col = j0 + (wn << 6) + (ni << 4) + l16;
#pragma unroll
            for (int r = 0; r < 4; ++r) {
                int row = m0 + (wm << 6) + (mi << 4) + (quad << 2) + r;
                Pp[(size_t)row * 256 + col] = f2bf(acc[mi][ni][r]);
            }
        }
}

// ---------------------------------------------------------------------------
// K3: fused split-K reduce (bf16 P) + noise + ReLU + MLP + log_softmax.
// 8 rows/block, 512 blocks. Weight-stationary threads.
// ---------------------------------------------------------------------------
__global__ __launch_bounds__(256) void k_mlp(
    const short* __restrict__ P,      // (8,4096,256) bf16
    const float* __restrict__ a_mat,  // (256,5,5)
    const float* __restrict__ noise,  // (256,5)
    const float* __restrict__ fc1_w, const float* __restrict__ fc1_b,
    const float* __restrict__ fc2_w, const float* __restrict__ fc2_b,
    const float* __restrict__ out_w, const float* __restrict__ out_b,
    float* __restrict__ out)          // (4096,10)
{
    __shared__ __align__(16) float Rt[8][260];
    __shared__ float P1[2][8][132];
    __shared__ __align__(16) float H2[8][132];
    __shared__ float P2[4][8][68];
    __shared__ __align__(16) float H3[8][68];
    __shared__ float LG[8][12];
    __shared__ float mrow[8], srow[8];
    __shared__ float nts[256];
    int t = threadIdx.x;
    int b0 = blockIdx.x * 8;

    // noise_term[j]
    {
        float nt = 0.f;
#pragma unroll
        for (int c = 0; c < 5; ++c) {
            float ar = 0.f;
#pragma unroll
            for (int m = 0; m < 5; ++m) ar += a_mat[t * 25 + c * 5 + m];
            nt += noise[t * 5 + c] * ar;
        }
        nts[t] = nt;
    }
    __syncthreads();

    // stage R rows: sum over 8 K-slices + noise + relu
    for (int i = t; i < 512; i += 256) {
        int r = i >> 6;
        int c4 = i & 63;
        size_t base = (size_t)(b0 + r) * 256 + c4 * 4;
        float4 sum = *(const float4*)&nts[c4 * 4];
#pragma unroll
        for (int ks = 0; ks < 8; ++ks) {
            short4 p = *(const short4*)(P + ((size_t)ks << 20) + base);
            sum.x += bf2f(p.x); sum.y += bf2f(p.y);
            sum.z += bf2f(p.z); sum.w += bf2f(p.w);
        }
        sum.x = fmaxf(sum.x, 0.f); sum.y = fmaxf(sum.y, 0.f);
        sum.z = fmaxf(sum.z, 0.f); sum.w = fmaxf(sum.w, 0.f);
        *(float4*)&Rt[r][c4 * 4] = sum;
    }
    __syncthreads();

    // fc1 partials: o = t&127, half = t>>7 (K-half of 128)
    {
        int o = t & 127, h = t >> 7;
        float acc[8];
#pragma unroll
        for (int r = 0; r < 8; ++r) acc[r] = 0.f;
        const float* wr = fc1_w + o * 256 + h * 128;
        for (int c = 0; c < 128; c += 4) {
            float4 wv = *(const float4*)(wr + c);
#pragma unroll
            for (int r = 0; r < 8; ++r) {
                float4 rv = *(const float4*)&Rt[r][h * 128 + c];
                acc[r] += rv.x * wv.x + rv.y * wv.y + rv.z * wv.z + rv.w * wv.w;
            }
        }
#pragma unroll
        for (int r = 0; r < 8; ++r) P1[h][r][o] = acc[r];
    }
    __syncthreads();

    for (int i = t; i < 1024; i += 256) {
        int r = i >> 7, o = i & 127;
        H2[r][o] = fmaxf(P1[0][r][o] + P1[1][r][o] + fc1_b[o], 0.f);
    }
    __syncthreads();

    // fc2 partials: o = t&63, q = t>>6 (K-quarter of 32)
    {
        int o = t & 63, q = t >> 6;
        float acc[8];
#pragma unroll
        for (int r = 0; r < 8; ++r) acc[r] = 0.f;
        const float* wr = fc2_w + o * 128 + q * 32;
        for (int c = 0; c < 32; c += 4) {
            float4 wv = *(const float4*)(wr + c);
#pragma unroll
            for (int r = 0; r < 8; ++r) {
                float4 rv = *(const float4*)&H2[r][q * 32 + c];
                acc[r] += rv.x * wv.x + rv.y * wv.y + rv.z * wv.z + rv.w * wv.w;
            }
        }
#pragma unroll
        for (int r = 0; r < 8; ++r) P2[q][r][o] = acc[r];
    }
    __syncthreads();

    for (int i = t; i < 512; i += 256) {
        int r = i >> 6, o = i & 63;
        H3[r][o] = fmaxf(P2[0][r][o] + P2[1][r][o] + P2[2][r][o] + P2[3][r][o]
                         + fc2_b[o], 0.f);
    }
    __syncthreads();

    if (t < 80) {
        int r = t & 7, o = t >> 3;
        float s = out_b[o];
        const float* wpt = out_w + o * 64;
        for (int c = 0; c < 64; c += 4) {
            float4 wv = *(const float4*)(wpt + c);
            float4 rv = *(const float4*)&H3[r][c];
            s += rv.x * wv.x + rv.y * wv.y + rv.z * wv.z + rv.w * wv.w;
        }
        LG[r][o] = s;
    }
    __syncthreads();

    if (t < 8) {
        float m = -1e30f;
#pragma unroll
        for (int o = 0; o < 10; ++o) m = fmaxf(m, LG[t][o]);
        float s = 0.f;
#pragma unroll
        for (int o = 0; o < 10; ++o) s += expf(LG[t][o] - m);
        mrow[t] = m;
        srow[t] = logf(s);
    }
    __syncthreads();

    if (t < 80) {
        int r = t & 7, o = t >> 3;
        out[(size_t)(b0 + r) * 10 + o] = LG[r][o] - mrow[r] - srow[r];
    }
}

// ---------------------------------------------------------------------------
extern "C" void kernel_launch(void* const* d_in, const int* in_sizes, int n_in,
                              void* d_out, int out_size, void* d_ws, size_t ws_size,
                              hipStream_t stream)
{
    const float* x           = (const float*)d_in[0];
    const float* conv_w      = (const float*)d_in[1];
    const float* conv_b      = (const float*)d_in[2];
    const float* bn_gamma    = (const float*)d_in[3];
    const float* bn_beta     = (const float*)d_in[4];
    const float* bn_mean     = (const float*)d_in[5];
    const float* bn_var      = (const float*)d_in[6];
    const float* cut_w_big   = (const float*)d_in[7];
    const float* cut_w_small = (const float*)d_in[8];
    const float* fc1_w       = (const float*)d_in[9];
    const float* fc1_b       = (const float*)d_in[10];
    const float* fc2_w       = (const float*)d_in[11];
    const float* fc2_b       = (const float*)d_in[12];
    const float* out_w       = (const float*)d_in[13];
    const float* out_b       = (const float*)d_in[14];
    const float* b_mat       = (const float*)d_in[15];
    const float* h_mat       = (const float*)d_in[16];
    const float* a_mat       = (const float*)d_in[17];
    const float* indicator   = (const float*)d_in[18];
    const float* noise       = (const float*)d_in[19];
    float* out = (float*)d_out;

    char* ws = (char*)d_ws;
    short* Fbf = (short*)ws;                     // 32 MB
    short* Wbf = (short*)(ws + 33554432);        // 2 MB
    short* Pbf = (short*)(ws + 35651584);        // 16 MB (8 x 1M bf16)

    k_prep<<<20480, 256, 0, stream>>>(x, conv_w, conv_b, bn_gamma, bn_beta,
                                      bn_mean, bn_var, cut_w_big, cut_w_small,
                                      b_mat, h_mat, a_mat, indicator, Fbf, Wbf);
    k_gemm<<<512, 256, 0, stream>>>(Fbf, Wbf, Pbf);
    k_mlp<<<512, 256, 0, stream>>>(Pbf, a_mat, noise, fc1_w, fc1_b, fc2_w, fc2_b,
                                   out_w, out_b, out);
}

// Round 3
// 370.027 us; speedup vs baseline: 1.0152x; 1.0043x over previous
//
#include <hip/hip_runtime.h>
#include <math.h>

typedef __attribute__((ext_vector_type(4))) float f32x4;

static __device__ __forceinline__ short f2bf(float f) {
    union { float f; unsigned u; } v; v.f = f;
    unsigned r = v.u + 0x7FFFu + ((v.u >> 16) & 1u);
    return (short)(r >> 16);
}

static __device__ __forceinline__ float bf2f(short s) {
    union { unsigned u; float f; } v;
    v.u = ((unsigned)(unsigned short)s) << 16;
    return v.f;
}

// Manual fp32 -> OCP e4m3fn, RNE, saturating at 448 (never emits NaN 0x7F).
// Uses only v_rndne/v_ldexp/int ops -- no fp8 cvt builtins.
static __device__ __forceinline__ unsigned f2e4m3(float x) {
    union { float f; unsigned u; } v; v.f = x;
    unsigned sign = (v.u >> 24) & 0x80u;
    float a = fminf(fabsf(x), 448.f);
    unsigned enc;
    if (a < 0.015625f) {                    // subnormal range, quantum 2^-9
        enc = (unsigned)(int)rintf(a * 512.f);   // 0..8 (8 == 2^-6 normal, encoding carries)
    } else {
        v.f = a;
        int e = (int)((v.u >> 23) & 0xffu) - 127;   // [-6, 8]
        int m = (int)rintf(ldexpf(a, 3 - e));        // [8, 16]
        int E = e + 7;
        if (m == 16) { m = 8; ++E; }                 // E stays <= 15 (a <= 448)
        enc = (unsigned)((E << 3) | (m - 8));
    }
    return sign | enc;
}

// fp8 scaling: W stored x256, F stored x16 (keeps both in e4m3 normal range;
// W_eff ~1e-3 std would otherwise be subnormal). GEMM epilogue divides by 4096.
#define FSCALE 16.0f
#define WSCALE 256.0f
#define PINV   (1.0f / 4096.0f)

// ---------------------------------------------------------------------------
// Physical k-layout of F / W columns (4096), co packed innermost:
//   big n in {0,1}:   phys = n*1024 + pos*4 + co    (pos 0..255)
//   small n in {2..9}: phys = 2048 + (n-2)*256 + pos*4 + co (pos 0..63)
// ---------------------------------------------------------------------------

// K0 (merged): blocks [0,4096) build W_eff (fp8); blocks [4096,20480) run the
// conv+BN+ReLU+pool branches writing F (fp8).
__global__ __launch_bounds__(256) void k_prep(
    const float* __restrict__ x,      // (4096,3,64,64)
    const float* __restrict__ conv_w, // (10,4,3,3,3)
    const float* __restrict__ conv_b,
    const float* __restrict__ bn_g,
    const float* __restrict__ bn_b,
    const float* __restrict__ bn_m,
    const float* __restrict__ bn_v,
    const float* __restrict__ cut_w_big,   // (2,256,1024)
    const float* __restrict__ cut_w_small, // (8,256,256)
    const float* __restrict__ b_mat,       // (10,256)
    const float* __restrict__ h_mat,       // (10,64,5)
    const float* __restrict__ a_mat,       // (256,5,5)
    const float* __restrict__ indicator,   // (256,64)
    unsigned char* __restrict__ F,    // (4096,4096) fp8 e4m3, x16 scale
    unsigned char* __restrict__ W)    // (256,4096) fp8 e4m3, x256 scale
{
    if (blockIdx.x < 4096) {
        // ---- W_eff build: W[j,k] = cut_w * coeff[n(k), j] * 256 ----
        int bx = blockIdx.x;
        int tid0 = bx << 8;
        int j = tid0 >> 12;               // block-uniform
        int kbase = tid0 & 4095;          // block-uniform
        int n = (kbase < 2048) ? (kbase >> 10) : 2 + ((kbase - 2048) >> 8);

        float arow[5];
#pragma unroll
        for (int c = 0; c < 5; ++c) {
            float s = 0.f;
#pragma unroll
            for (int m = 0; m < 5; ++m) s += a_mat[j * 25 + c * 5 + m];
            arow[c] = s;
        }
        int lane = threadIdx.x & 63;
        float hs = 0.f;
#pragma unroll
        for (int c = 0; c < 5; ++c) hs += h_mat[(n * 64 + lane) * 5 + c] * arow[c];
        float v = indicator[j * 64 + lane] * hs;
#pragma unroll
        for (int off = 32; off >= 1; off >>= 1) v += __shfl_xor(v, off);
        float coeff = b_mat[n * 256 + j] * v;

        int tid = tid0 + threadIdx.x;
        int k = tid & 4095;
        float w;
        if (k < 2048) {
            int nn = k >> 10;
            int r = k & 1023;
            int pos = r >> 2, co = r & 3;
            w = cut_w_big[((nn * 256 + j) << 10) + co * 256 + pos];
        } else {
            int kk2 = k - 2048;
            int nn = kk2 >> 8;
            int r = kk2 & 255;
            int pos = r >> 2, co = r & 3;
            w = cut_w_small[((nn * 256 + j) << 8) + co * 64 + pos];
        }
        W[tid] = (unsigned char)f2e4m3(w * coeff * WSCALE);
        return;
    }

    // ---- conv branches ----
    // big:   per ci: E[34][24] + O[34][24] = 1632 floats, x3 = 4896
    // small: per page (ci*4+img): E[18][12]+O[18][12] = 432, x12 = 5184
    __shared__ __align__(16) float in_s[5184];
    __shared__ float bn_a[4], bn_c[4];
    int t = threadIdx.x;
    int bx = blockIdx.x - 4096;

    if (bx < 8192) {
        // ---- big branch: 32x32 slice, 1 image/block ----
        int n = bx >> 12;
        int b = bx & 4095;
        int r0 = 32 * n;
        // full-tile zero (4896 floats = 1224 float4)
        {
            float4 z4 = make_float4(0.f, 0.f, 0.f, 0.f);
            float4* zp = (float4*)in_s;
            for (int i = t; i < 1224; i += 256) zp[i] = z4;
        }
        if (t < 4) {
            float scale = bn_g[n * 4 + t] * rsqrtf(bn_v[n * 4 + t] + 1e-5f);
            bn_a[t] = scale;
            bn_c[t] = (conv_b[n * 4 + t] - bn_m[n * 4 + t]) * scale + bn_b[n * 4 + t];
        }
        __syncthreads();
        // stage interior rows 1..32: 768 float4 (3/thread)
        for (int i = t; i < 768; i += 256) {
            int ci = i >> 8, rem = i & 255, yy = rem >> 3, xq = rem & 7;
            float4 v = *(const float4*)(x + ((size_t)(b * 3 + ci) * 64 + r0 + yy) * 64 + xq * 4);
            int eb = ci * 1632 + (yy + 1) * 24;
            int ob = eb + 816;
            *(float2*)&in_s[eb + 2 * xq] = make_float2(v.x, v.z);   // E[2xq],E[2xq+1]
            in_s[ob + 2 * xq + 1] = v.y;                            // O: col 4xq+1
            in_s[ob + 2 * xq + 2] = v.w;                            // O: col 4xq+3
        }
        __syncthreads();

        int py = t >> 4, px = t & 15;
        float s[4][4];
#pragma unroll
        for (int a = 0; a < 4; ++a)
#pragma unroll
            for (int p = 0; p < 4; ++p) s[a][p] = 0.f;
        const float* wp = conv_w + n * 108;
#pragma unroll
        for (int ci = 0; ci < 3; ++ci) {
            float wv[16];
#pragma unroll
            for (int dy = 0; dy < 4; ++dy) {
                int rowb = ci * 1632 + (2 * py + dy) * 24 + px;
                float e0 = in_s[rowb];            // col 2px
                float e1 = in_s[rowb + 1];        // col 2px+2
                float o0 = in_s[rowb + 816];      // col 2px-1
                float o1 = in_s[rowb + 817];      // col 2px+1
                wv[dy * 4 + 0] = o0; wv[dy * 4 + 1] = e0;
                wv[dy * 4 + 2] = o1; wv[dy * 4 + 3] = e1;
            }
#pragma unroll
            for (int co = 0; co < 4; ++co) {
                const float* kk = wp + co * 27 + ci * 9;
                float k0 = kk[0], k1 = kk[1], k2 = kk[2], k3 = kk[3], k4 = kk[4],
                      k5 = kk[5], k6 = kk[6], k7 = kk[7], k8 = kk[8];
                s[co][0] += wv[0] * k0 + wv[1] * k1 + wv[2] * k2 + wv[4] * k3 + wv[5] * k4 + wv[6] * k5 + wv[8] * k6 + wv[9] * k7 + wv[10] * k8;
                s[co][1] += wv[1] * k0 + wv[2] * k1 + wv[3] * k2 + wv[5] * k3 + wv[6] * k4 + wv[7] * k5 + wv[9] * k6 + wv[10] * k7 + wv[11] * k8;
                s[co][2] += wv[4] * k0 + wv[5] * k1 + wv[6] * k2 + wv[8] * k3 + wv[9] * k4 + wv[10] * k5 + wv[12] * k6 + wv[13] * k7 + wv[14] * k8;
                s[co][3] += wv[5] * k0 + wv[6] * k1 + wv[7] * k2 + wv[9] * k3 + wv[10] * k4 + wv[11] * k5 + wv[13] * k6 + wv[14] * k7 + wv[15] * k8;
            }
        }
        unsigned pk8;
        {
            float m[4];
#pragma unroll
            for (int co = 0; co < 4; ++co) {
                float a = bn_a[co], c2 = bn_c[co];
                float v0 = fmaxf(s[co][0] * a + c2, 0.f);
                float v1 = fmaxf(s[co][1] * a + c2, 0.f);
                float v2 = fmaxf(s[co][2] * a + c2, 0.f);
                float v3 = fmaxf(s[co][3] * a + c2, 0.f);
                m[co] = fmaxf(fmaxf(v0, v1), fmaxf(v2, v3)) * FSCALE;
            }
            pk8 = f2e4m3(m[0]) | (f2e4m3(m[1]) << 8)
                | (f2e4m3(m[2]) << 16) | (f2e4m3(m[3]) << 24);
        }
        *(unsigned*)&F[(size_t)b * 4096 + n * 1024 + t * 4] = pk8;
    } else {
        // ---- small branches: 16x16 slices, 4 images/block ----
        int i2 = bx - 8192;
        int n = 2 + (i2 >> 10);
        int g = i2 & 1023;
        int b0 = g * 4;
        int r0 = 16 * ((n - 2) & 3);
        int c0 = 32 + 16 * ((n - 2) >> 2);
        // full-tile zero (5184 floats = 1296 float4)
        {
            float4 z4 = make_float4(0.f, 0.f, 0.f, 0.f);
            float4* zp = (float4*)in_s;
            for (int i = t; i < 1296; i += 256) zp[i] = z4;
        }
        if (t < 4) {
            float scale = bn_g[n * 4 + t] * rsqrtf(bn_v[n * 4 + t] + 1e-5f);
            bn_a[t] = scale;
            bn_c[t] = (conv_b[n * 4 + t] - bn_m[n * 4 + t]) * scale + bn_b[n * 4 + t];
        }
        __syncthreads();
        // stage interior: 768 float4 (3/thread), page = ci*4+img
        for (int i = t; i < 768; i += 256) {
            int page = i >> 6, rem = i & 63, yy = rem >> 2, xq = rem & 3;
            int ci = page >> 2, img = page & 3;
            float4 v = *(const float4*)(x + ((size_t)((b0 + img) * 3 + ci) * 64 + r0 + yy) * 64 + c0 + xq * 4);
            int eb = page * 432 + (yy + 1) * 12;
            int ob = eb + 216;
            *(float2*)&in_s[eb + 2 * xq] = make_float2(v.x, v.z);
            in_s[ob + 2 * xq + 1] = v.y;
            in_s[ob + 2 * xq + 2] = v.w;
        }
        __syncthreads();

        int img = t >> 6;
        int pos = t & 63;
        int py = pos >> 3, px = pos & 7;
        float s[4][4];
#pragma unroll
        for (int a = 0; a < 4; ++a)
#pragma unroll
            for (int p = 0; p < 4; ++p) s[a][p] = 0.f;
        const float* wp = conv_w + n * 108;
#pragma unroll
        for (int ci = 0; ci < 3; ++ci) {
            float wv[16];
            int pageb = (ci * 4 + img) * 432;
#pragma unroll
            for (int dy = 0; dy < 4; ++dy) {
                int rowb = pageb + (2 * py + dy) * 12 + px;
                float e0 = in_s[rowb];
                float e1 = in_s[rowb + 1];
                float o0 = in_s[rowb + 216];
                float o1 = in_s[rowb + 217];
                wv[dy * 4 + 0] = o0; wv[dy * 4 + 1] = e0;
                wv[dy * 4 + 2] = o1; wv[dy * 4 + 3] = e1;
            }
#pragma unroll
            for (int co = 0; co < 4; ++co) {
                const float* kk = wp + co * 27 + ci * 9;
                float k0 = kk[0], k1 = kk[1], k2 = kk[2], k3 = kk[3], k4 = kk[4],
                      k5 = kk[5], k6 = kk[6], k7 = kk[7], k8 = kk[8];
                s[co][0] += wv[0] * k0 + wv[1] * k1 + wv[2] * k2 + wv[4] * k3 + wv[5] * k4 + wv[6] * k5 + wv[8] * k6 + wv[9] * k7 + wv[10] * k8;
                s[co][1] += wv[1] * k0 + wv[2] * k1 + wv[3] * k2 + wv[5] * k3 + wv[6] * k4 + wv[7] * k5 + wv[9] * k6 + wv[10] * k7 + wv[11] * k8;
                s[co][2] += wv[4] * k0 + wv[5] * k1 + wv[6] * k2 + wv[8] * k3 + wv[9] * k4 + wv[10] * k5 + wv[12] * k6 + wv[13] * k7 + wv[14] * k8;
                s[co][3] += wv[5] * k0 + wv[6] * k1 + wv[7] * k2 + wv[9] * k3 + wv[10] * k4 + wv[11] * k5 + wv[13] * k6 + wv[14] * k7 + wv[15] * k8;
            }
        }
        unsigned pk8;
        {
            float m[4];
#pragma unroll
            for (int co = 0; co < 4; ++co) {
                float a = bn_a[co], c2 = bn_c[co];
                float v0 = fmaxf(s[co][0] * a + c2, 0.f);
                float v1 = fmaxf(s[co][1] * a + c2, 0.f);
                float v2 = fmaxf(s[co][2] * a + c2, 0.f);
                float v3 = fmaxf(s[co][3] * a + c2, 0.f);
                m[co] = fmaxf(fmaxf(v0, v1), fmaxf(v2, v3)) * FSCALE;
            }
            pk8 = f2e4m3(m[0]) | (f2e4m3(m[1]) << 8)
                | (f2e4m3(m[2]) << 16) | (f2e4m3(m[3]) << 24);
        }
        *(unsigned*)&F[(size_t)(b0 + img) * 4096 + 2048 + (n - 2) * 256 + pos * 4] = pk8;
    }
}

// ---------------------------------------------------------------------------
// K2: fp8 MFMA GEMM, split-K=8. Staging halves vs bf16 (64 B/row K-tiles).
// LDS swizzle: 8B slot u -> u ^ (row & 6). Bit0 untouched keeps 16B write
// contiguity for global_load_lds; read ds_read_b64 lands 2 lanes/bank (free).
// ---------------------------------------------------------------------------
__global__ __launch_bounds__(256) void k_gemm(
    const unsigned char* __restrict__ F, // (4096,4096) fp8, x16
    const unsigned char* __restrict__ W, // (256,4096) fp8, x256
    short* __restrict__ P)               // (8,4096,256) bf16, true scale
{
    __shared__ __align__(16) unsigned char As[128 * 64];
    __shared__ __align__(16) unsigned char Bs[128 * 64];
    int bx = blockIdx.x;          // 512 = 32 mtiles x 2 jtiles x 8 ksplit
    int mt = bx & 31;
    int jt = (bx >> 5) & 1;
    int ks = bx >> 6;
    int t = threadIdx.x;
    int m0 = mt << 7, j0 = jt << 7;

    int lane = t & 63;
    int wave = t >> 6;
    int wm = wave & 1, wn = wave >> 1;
    int l16 = lane & 15, quad = lane >> 4;

    f32x4 acc[4][4];
#pragma unroll
    for (int i = 0; i < 4; ++i)
#pragma unroll
        for (int j = 0; j < 4; ++j) acc[i][j] = (f32x4){0.f, 0.f, 0.f, 0.f};

    for (int it = 0; it < 8; ++it) {
        int k0 = (ks << 9) + (it << 6);   // fp8 element == byte offset
#pragma unroll
        for (int r = 0; r < 2; ++r) {
            int c = (r << 8) + t;         // 0..511 : 128 rows x 4 16B-slots
            int row = c >> 2, sl = c & 3;
            int gsl = sl ^ ((row >> 1) & 3);   // source pre-swizzle (16B units)
            const unsigned char* gpA = F + ((size_t)(m0 + row) << 12) + k0 + (gsl << 4);
            const unsigned char* gpB = W + ((size_t)(j0 + row) << 12) + k0 + (gsl << 4);
            __builtin_amdgcn_global_load_lds(
                (const __attribute__((address_space(1))) void*)gpA,
                (__attribute__((address_space(3))) void*)(As + (c << 4)), 16, 0, 0);
            __builtin_amdgcn_global_load_lds(
                (const __attribute__((address_space(1))) void*)gpB,
                (__attribute__((address_space(3))) void*)(Bs + (c << 4)), 16, 0, 0);
        }
        __syncthreads();
#pragma unroll
        for (int ks2 = 0; ks2 < 2; ++ks2) {
            long long af[4], bfr[4];
#pragma unroll
            for (int mi = 0; mi < 4; ++mi) {
                int row = (wm << 6) + (mi << 4) + l16;
                int q = (ks2 << 2) + quad;         // 8B k-slot 0..7
                int sl = q ^ (row & 6);            // read-side swizzle
                af[mi] = *(const long long*)&As[(row << 6) + (sl << 3)];
            }
#pragma unroll
            for (int ni = 0; ni < 4; ++ni) {
                int row = (wn << 6) + (ni << 4) + l16;
                int q = (ks2 << 2) + quad;
                int sl = q ^ (row & 6);
                bfr[ni] = *(const long long*)&Bs[(row << 6) + (sl << 3)];
            }
#pragma unroll
            for (int mi = 0; mi < 4; ++mi)
#pragma unroll
                for (int ni = 0; ni < 4; ++ni)
                    acc[mi][ni] = __builtin_amdgcn_mfma_f32_16x16x32_fp8_fp8(
                        af[mi], bfr[ni], acc[mi][ni], 0, 0, 0);
        }
        __syncthreads();
    }

    short* Pp = P + ((size_t)ks << 20);
#pragma unroll
    for (int mi = 0; mi < 4; ++mi)
#pragma unroll
        for (int ni = 0; ni < 4; ++ni) {
            int col = j0 + (wn << 6) + (ni << 4) + l16;
#pragma unroll
            for (int r = 0; r < 4; ++r) {
                int row = m0 + (wm << 6) + (mi << 4) + (quad << 2) + r;
                Pp[(size_t)row * 256 + col] = f2bf(acc[mi][ni][r] * PINV);
            }
        }
}

// ---------------------------------------------------------------------------
// K3: fused split-K reduce (bf16 P) + noise + ReLU + MLP + log_softmax.
// 8 rows/block, 512 blocks. Weight-stationary threads.
// ---------------------------------------------------------------------------
__global__ __launch_bounds__(256) void k_mlp(
    const short* __restrict__ P,      // (8,4096,256) bf16
    const float* __restrict__ a_mat,  // (256,5,5)
    const float* __restrict__ noise,  // (256,5)
    const float* __restrict__ fc1_w, const float* __restrict__ fc1_b,
    const float* __restrict__ fc2_w, const float* __restrict__ fc2_b,
    const float* __restrict__ out_w, const float* __restrict__ out_b,
    float* __restrict__ out)          // (4096,10)
{
    __shared__ __align__(16) float Rt[8][260];
    __shared__ float P1[2][8][132];
    __shared__ __align__(16) float H2[8][132];
    __shared__ float P2[4][8][68];
    __shared__ __align__(16) float H3[8][68];
    __shared__ float LG[8][12];
    __shared__ float mrow[8], srow[8];
    __shared__ float nts[256];
    int t = threadIdx.x;
    int b0 = blockIdx.x * 8;

    // noise_term[j]
    {
        float nt = 0.f;
#pragma unroll
        for (int c = 0; c < 5; ++c) {
            float ar = 0.f;
#pragma unroll
            for (int m = 0; m < 5; ++m) ar += a_mat[t * 25 + c * 5 + m];
            nt += noise[t * 5 + c] * ar;
        }
        nts[t] = nt;
    }
    __syncthreads();

    // stage R rows: sum over 8 K-slices + noise + relu
    for (int i = t; i < 512; i += 256) {
        int r = i >> 6;
        int c4 = i & 63;
        size_t base = (size_t)(b0 + r) * 256 + c4 * 4;
        float4 sum = *(const float4*)&nts[c4 * 4];
#pragma unroll
        for (int ks = 0; ks < 8; ++ks) {
            short4 p = *(const short4*)(P + ((size_t)ks << 20) + base);
            sum.x += bf2f(p.x); sum.y += bf2f(p.y);
            sum.z += bf2f(p.z); sum.w += bf2f(p.w);
        }
        sum.x = fmaxf(sum.x, 0.f); sum.y = fmaxf(sum.y, 0.f);
        sum.z = fmaxf(sum.z, 0.f); sum.w = fmaxf(sum.w, 0.f);
        *(float4*)&Rt[r][c4 * 4] = sum;
    }
    __syncthreads();

    // fc1 partials: o = t&127, half = t>>7 (K-half of 128)
    {
        int o = t & 127, h = t >> 7;
        float acc[8];
#pragma unroll
        for (int r = 0; r < 8; ++r) acc[r] = 0.f;
        const float* wr = fc1_w + o * 256 + h * 128;
        for (int c = 0; c < 128; c += 4) {
            float4 wv = *(const float4*)(wr + c);
#pragma unroll
            for (int r = 0; r < 8; ++r) {
                float4 rv = *(const float4*)&Rt[r][h * 128 + c];
                acc[r] += rv.x * wv.x + rv.y * wv.y + rv.z * wv.z + rv.w * wv.w;
            }
        }
#pragma unroll
        for (int r = 0; r < 8; ++r) P1[h][r][o] = acc[r];
    }
    __syncthreads();

    for (int i = t; i < 1024; i += 256) {
        int r = i >> 7, o = i & 127;
        H2[r][o] = fmaxf(P1[0][r][o] + P1[1][r][o] + fc1_b[o], 0.f);
    }
    __syncthreads();

    // fc2 partials: o = t&63, q = t>>6 (K-quarter of 32)
    {
        int o = t & 63, q = t >> 6;
        float acc[8];
#pragma unroll
        for (int r = 0; r < 8; ++r) acc[r] = 0.f;
        const float* wr = fc2_w + o * 128 + q * 32;
        for (int c = 0; c < 32; c += 4) {
            float4 wv = *(const float4*)(wr + c);
#pragma unroll
            for (int r = 0; r < 8; ++r) {
                float4 rv = *(const float4*)&H2[r][q * 32 + c];
                acc[r] += rv.x * wv.x + rv.y * wv.y + rv.z * wv.z + rv.w * wv.w;
            }
        }
#pragma unroll
        for (int r = 0; r < 8; ++r) P2[q][r][o] = acc[r];
    }
    __syncthreads();

    for (int i = t; i < 512; i += 256) {
        int r = i >> 6, o = i & 63;
        H3[r][o] = fmaxf(P2[0][r][o] + P2[1][r][o] + P2[2][r][o] + P2[3][r][o]
                         + fc2_b[o], 0.f);
    }
    __syncthreads();

    if (t < 80) {
        int r = t & 7, o = t >> 3;
        float s = out_b[o];
        const float* wpt = out_w + o * 64;
        for (int c = 0; c < 64; c += 4) {
            float4 wv = *(const float4*)(wpt + c);
            float4 rv = *(const float4*)&H3[r][c];
            s += rv.x * wv.x + rv.y * wv.y + rv.z * wv.z + rv.w * wv.w;
        }
        LG[r][o] = s;
    }
    __syncthreads();

    if (t < 8) {
        float m = -1e30f;
#pragma unroll
        for (int o = 0; o < 10; ++o) m = fmaxf(m, LG[t][o]);
        float s = 0.f;
#pragma unroll
        for (int o = 0; o < 10; ++o) s += expf(LG[t][o] - m);
        mrow[t] = m;
        srow[t] = logf(s);
    }
    __syncthreads();

    if (t < 80) {
        int r = t & 7, o = t >> 3;
        out[(size_t)(b0 + r) * 10 + o] = LG[r][o] - mrow[r] - srow[r];
    }
}

// ---------------------------------------------------------------------------
extern "C" void kernel_launch(void* const* d_in, const int* in_sizes, int n_in,
                              void* d_out, int out_size, void* d_ws, size_t ws_size,
                              hipStream_t stream)
{
    const float* x           = (const float*)d_in[0];
    const float* conv_w      = (const float*)d_in[1];
    const float* conv_b      = (const float*)d_in[2];
    const float* bn_gamma    = (const float*)d_in[3];
    const float* bn_beta     = (const float*)d_in[4];
    const float* bn_mean     = (const float*)d_in[5];
    const float* bn_var      = (const float*)d_in[6];
    const float* cut_w_big   = (const float*)d_in[7];
    const float* cut_w_small = (const float*)d_in[8];
    const float* fc1_w       = (const float*)d_in[9];
    const float* fc1_b       = (const float*)d_in[10];
    const float* fc2_w       = (const float*)d_in[11];
    const float* fc2_b       = (const float*)d_in[12];
    const float* out_w       = (const float*)d_in[13];
    const float* out_b       = (const float*)d_in[14];
    const float* b_mat       = (const float*)d_in[15];
    const float* h_mat       = (const float*)d_in[16];
    const float* a_mat       = (const float*)d_in[17];
    const float* indicator   = (const float*)d_in[18];
    const float* noise       = (const float*)d_in[19];
    float* out = (float*)d_out;

    char* ws = (char*)d_ws;
    unsigned char* Ff8 = (unsigned char*)ws;               // 16 MB
    unsigned char* Wf8 = (unsigned char*)(ws + 16777216);  // 1 MB
    short* Pbf = (short*)(ws + 17825792);                  // 16 MB (8 x 1M bf16)

    k_prep<<<20480, 256, 0, stream>>>(x, conv_w, conv_b, bn_gamma, bn_beta,
                                      bn_mean, bn_var, cut_w_big, cut_w_small,
                                      b_mat, h_mat, a_mat, indicator, Ff8, Wf8);
    k_gemm<<<512, 256, 0, stream>>>(Ff8, Wf8, Pbf);
    k_mlp<<<512, 256, 0, stream>>>(Pbf, a_mat, noise, fc1_w, fc1_b, fc2_w, fc2_b,
                                   out_w, out_b, out);
}